// Round 26
// baseline (271.355 us; speedup 1.0000x reference)
//
#include <hip/hip_runtime.h>

// R26 — store-dense variant of the PASSING R25 kernel (bit-exact semantics).
// R25 passed (absmax 0.0): ref = XLA f32, thr = fmaf(thr,0.9f,0.1f*|x|),
// layout [B,T,F], out f32. rocprof: our kernel < 166us (absent from top-5,
// which is all 168us harness poison-fills) => dur_us 260 includes harness
// fills; kernel is ~48us (roofline) or ~90us (store-issue-bound), ambiguous.
// This round: same per-element op sequence (add -> >= -> zero-reset -> fmaf),
// but spikes precomputed into u32 masks (pure-VALU phase, 8 ILP chains),
// then a dense store loop (2x dwordx4 per t, ~19 VALU per 32B vs ~80 in R25).
// Differential read: dur_us drop = real kernel gain; flat = R25 was at
// roofline (declare next round).

#define TSTEPS 32
#define BDIM 32
#define FDIM 65536

typedef unsigned int u32;

__global__ __launch_bounds__(256) void spike_mask_kernel(
    const float* __restrict__ x, float* __restrict__ out) {
    int gid = blockIdx.x * blockDim.x + threadIdx.x;   // 0 .. B*F/8-1
    int fi  = gid & (FDIM / 8 - 1);                    // 0..8191
    int b   = gid >> 13;                               // F/8 = 8192
    int f   = fi << 3;

    const float4 x0 = *reinterpret_cast<const float4*>(x + (size_t)b * FDIM + f);
    const float4 x1 = *reinterpret_cast<const float4*>(x + (size_t)b * FDIM + f + 4);
    float xs[8] = {x0.x, x0.y, x0.z, x0.w, x1.x, x1.y, x1.z, x1.w};

    // ---- compute phase: 8 independent recurrences -> 32-bit spike masks ----
    u32 mk[8];
#pragma unroll
    for (int e = 0; e < 8; ++e) {
        float acc = 0.0f, thr = 0.5f;
        const float ad = 0.1f * fabsf(xs[e]);   // one rounding (matches ref)
        u32 m = 0;
#pragma unroll
        for (int t = 0; t < TSTEPS; ++t) {
            acc = acc + xs[e];
            bool s = acc >= thr;
            m |= (s ? 1u : 0u) << t;
            acc = s ? 0.0f : acc;
            thr = __builtin_fmaf(thr, 0.9f, ad);   // fused, single rounding
        }
        mk[e] = m;
    }

    // ---- store phase: dense 32B-per-t stream (64 dwordx4 stores back-to-back)
    float* outb = out + (size_t)b * TSTEPS * FDIM + f;
#pragma unroll
    for (int t = 0; t < TSTEPS; ++t) {
        float4 s0, s1;
        s0.x = ((mk[0] >> t) & 1u) ? 1.0f : 0.0f;
        s0.y = ((mk[1] >> t) & 1u) ? 1.0f : 0.0f;
        s0.z = ((mk[2] >> t) & 1u) ? 1.0f : 0.0f;
        s0.w = ((mk[3] >> t) & 1u) ? 1.0f : 0.0f;
        s1.x = ((mk[4] >> t) & 1u) ? 1.0f : 0.0f;
        s1.y = ((mk[5] >> t) & 1u) ? 1.0f : 0.0f;
        s1.z = ((mk[6] >> t) & 1u) ? 1.0f : 0.0f;
        s1.w = ((mk[7] >> t) & 1u) ? 1.0f : 0.0f;
        *reinterpret_cast<float4*>(outb + (size_t)t * FDIM)     = s0;
        *reinterpret_cast<float4*>(outb + (size_t)t * FDIM + 4) = s1;
    }
}

extern "C" void kernel_launch(void* const* d_in, const int* in_sizes, int n_in,
                              void* d_out, int out_size, void* d_ws, size_t ws_size,
                              hipStream_t stream) {
    (void)in_sizes; (void)n_in; (void)d_ws; (void)ws_size; (void)out_size;
    const float* x = (const float*)d_in[0];
    float* out     = (float*)d_out;
    const int total_threads = BDIM * FDIM / 8;   // 262144
    spike_mask_kernel<<<total_threads / 256, 256, 0, stream>>>(x, out);
}